// Round 3
// baseline (204.226 us; speedup 1.0000x reference)
//
#include <hip/hip_runtime.h>
#include <hip/hip_bf16.h>

typedef __attribute__((ext_vector_type(8))) short short8;
typedef __attribute__((ext_vector_type(4))) float f32x4;
typedef __attribute__((ext_vector_type(16))) float f32x16;

#define WS_B0_OFFSET  18874368u   // b0 after Wt (9*1024*1024 bf16)

// ---------------- Phase 0a: W[d][i][o] fp32 -> Wt[d][o][i] bf16 ----------------
__global__ void wt_kernel(const float* __restrict__ W, short* __restrict__ Wt) {
    __shared__ float t[64 * 65];
    int bid = blockIdx.x;
    int d   = bid >> 8;
    int rem = bid & 255;
    int i0  = (rem >> 4) << 6;
    int o0  = (rem & 15) << 6;
    const float* src = W + (size_t)d * 1048576;
    short* dst = Wt + (size_t)d * 1048576;
    int c  = threadIdx.x & 63;
    int rb = threadIdx.x >> 6;
#pragma unroll
    for (int k = 0; k < 16; k++) {
        int il = rb * 16 + k;
        t[il * 65 + c] = src[(size_t)(i0 + il) * 1024 + o0 + c];
    }
    __syncthreads();
#pragma unroll
    for (int k = 0; k < 16; k++) {
        int ol = rb * 16 + k;
        float v = t[c * 65 + ol];
        dst[(size_t)(o0 + ol) * 1024 + i0 + c] =
            (short)__bfloat16_as_ushort(__float2bfloat16(v));
    }
}

// ---------------- Phase 0b: b0[o] = sum_i W[0][i][o], two-stage ----------------
__global__ void colsum1(const float* __restrict__ W, float* __restrict__ part) {
    int s = blockIdx.x >> 2;
    int o = (blockIdx.x & 3) * 256 + threadIdx.x;
    const float* p = W + (size_t)s * 32 * 1024 + o;
    float acc = 0.f;
#pragma unroll
    for (int i = 0; i < 32; i++) acc += p[(size_t)i * 1024];
    part[s * 1024 + o] = acc;
}
__global__ void colsum2(const float* __restrict__ part, float* __restrict__ b0) {
    int o = blockIdx.x * 256 + threadIdx.x;
    float acc = 0.f;
#pragma unroll
    for (int s = 0; s < 32; s++) acc += part[s * 1024 + o];
    b0[o] = acc;
}

__device__ __forceinline__ float fast_tanh(float t) {
    float e = __expf(t + t);
    return 1.0f - 2.0f * __builtin_amdgcn_rcpf(e + 1.0f);
}

// ---------------- Phase 1: fused tanh + Chebyshev + GEMM ----------------
// 512 thr = 8 waves (2 wr x 4 wc), wave = 64x64 (2x2 of 32x32x16 MFMA).
// Tile 128x256, BK=32. A (bf16 T_d tile) double-buffered in LDS, written by
// per-thread register recurrence; B triple-buffered via global_load_lds.
// One barrier per degree-step, counted vmcnt.
extern "C" __global__ void __launch_bounds__(512, 2)
cheby_gemm(const float* __restrict__ x, const short* __restrict__ Wt,
           const float* __restrict__ b0v, const float* __restrict__ scp,
           const float* __restrict__ bip, float* __restrict__ out) {
    // LDS map: A bufs @0,8192 (each 128row x 32k bf16, [c][slot][16B]);
    //          B bufs @16384 + {0,1,2}*16384 ([c][col][16B])
    __shared__ __align__(16) char lds[65536];

    const int tid = threadIdx.x, lane = tid & 63, wid = tid >> 6;
    const int wr = wid >> 2, wc = wid & 3;
    const int tn = blockIdx.x & 3, tm = blockIdx.x >> 2;  // bid%8 -> fixed tn per XCD
    const int m0 = tm << 7, n0 = tn << 8;
    const float sc = scp[0], bi = bip[0];

    // ---- A ownership: row = tid>>2 (0..127), c-chunk = tid&3 (8 k elems) ----
    const int arow = tid >> 2, ac = tid & 3;
    const int wbyte0 = ac * 2048 + ((arow ^ (ac << 1)) << 4);
    const float* xptr = x + (size_t)(m0 + arow) * 1024 + ac * 8;

    // ---- A-frag read bases (kh = k-half) ----
    int abase[2];
#pragma unroll
    for (int kh = 0; kh < 2; kh++) {
        int rr = wr * 64 + (lane & 31);
        int c  = kh * 2 + (lane >> 5);
        abase[kh] = c * 2048 + ((rr ^ ((c & 3) << 1)) << 4);
    }
    // ---- B-frag read bases ----
    int bbase[2];
#pragma unroll
    for (int kh = 0; kh < 2; kh++) {
        int cc = wc * 64 + (lane & 31);
        int c  = kh * 2 + (lane >> 5);
        bbase[kh] = 16384 + ((c * 256 + cc) << 4);
    }
    // ---- B staging constants (2 rounds x 512 thr x 16B = 16KB) ----
    int coloff[2], ldsoff[2];
#pragma unroll
    for (int r = 0; r < 2; r++) {
        int s = r * 512 + tid;
        int c = s >> 8, col = s & 255;
        coloff[r] = ((n0 + col) << 10) + c * 8;
        ldsoff[r] = 16384 + ((r * 512 + (tid & ~63)) << 4);
    }

    auto stageB = [&](int dd, int icc, int bf) {
        const short* wp = Wt + ((size_t)dd << 20) + (icc << 5);
#pragma unroll
        for (int r = 0; r < 2; r++)
            __builtin_amdgcn_global_load_lds(
                (const __attribute__((address_space(1))) void*)(wp + coloff[r]),
                (__attribute__((address_space(3))) void*)(lds + bf * 16384 + ldsoff[r]),
                16, 0, 0);
    };

    f32x4 xv0, xv1;
    auto loadx = [&](int icc) {
        const float* p = xptr + (icc << 5);
        xv0 = *(const f32x4*)p;
        xv1 = *(const f32x4*)(p + 4);
    };

    float x2[8], tA[8], tB[8];
    auto dotanh = [&]() {
#pragma unroll
        for (int j = 0; j < 4; j++) {
            tA[j]     = fast_tanh(fmaf(xv0[j], sc, bi));
            tA[j + 4] = fast_tanh(fmaf(xv1[j], sc, bi));
        }
#pragma unroll
        for (int j = 0; j < 8; j++) x2[j] = tA[j] + tA[j];
    };
    auto writeA = [&](const float* t, int wbuf) {
        short8 v;
#pragma unroll
        for (int j = 0; j < 8; j++)
            v[j] = (short)__bfloat16_as_ushort(__float2bfloat16(t[j]));
        *(short8*)(lds + wbuf * 8192 + wbyte0) = v;
    };

    f32x16 acc[2][2];
#pragma unroll
    for (int n = 0; n < 2; n++) {
        float v = b0v[n0 + wc * 64 + n * 32 + (lane & 31)];   // degree-0 folded in
        f32x16 a;
#pragma unroll
        for (int r = 0; r < 16; r++) a[r] = v;
        acc[0][n] = a;
        acc[1][n] = a;
    }

    auto domfma = [&](int rbuf, int abuf) {
        short8 af[2][2], bfr[2][2];
#pragma unroll
        for (int m = 0; m < 2; m++)
#pragma unroll
            for (int kh = 0; kh < 2; kh++)
                af[m][kh] = *(const short8*)(lds + abuf * 8192 + abase[kh] + m * 512);
#pragma unroll
        for (int n = 0; n < 2; n++)
#pragma unroll
            for (int kh = 0; kh < 2; kh++)
                bfr[n][kh] = *(const short8*)(lds + rbuf * 16384 + bbase[kh] + n * 512);
        __builtin_amdgcn_s_setprio(1);
#pragma unroll
        for (int m = 0; m < 2; m++)
#pragma unroll
            for (int n = 0; n < 2; n++)
#pragma unroll
                for (int kh = 0; kh < 2; kh++)
                    acc[m][n] = __builtin_amdgcn_mfma_f32_32x32x16_bf16(
                        af[m][kh], bfr[n][kh], acc[m][n], 0, 0, 0);
        __builtin_amdgcn_s_setprio(0);
    };

    int rbuf = 0;
#define STEP_END(VM)                                                     \
    __builtin_amdgcn_sched_barrier(0);                                   \
    asm volatile("s_waitcnt vmcnt(" #VM ") lgkmcnt(0)" ::: "memory");    \
    __builtin_amdgcn_s_barrier();                                        \
    __builtin_amdgcn_sched_barrier(0);                                   \
    rbuf = rbuf + 1; if (rbuf >= 3) rbuf -= 3;

#define SBUF int sbuf = rbuf + 2; if (sbuf >= 3) sbuf -= 3;

    // ---- prologue: x(ic0) -> tanh -> T1 in A-buf1; B_1 -> buf0, B_2 -> buf1 ----
    loadx(0);
    stageB(1, 0, 0);
    stageB(2, 0, 1);
    dotanh();
    writeA(tA, 1);
    __builtin_amdgcn_sched_barrier(0);
    asm volatile("s_waitcnt vmcnt(2) lgkmcnt(0)" ::: "memory");
    __builtin_amdgcn_s_barrier();
    __builtin_amdgcn_sched_barrier(0);

    for (int ic = 0; ic < 32; ++ic) {
        const int icn = ic < 31 ? ic + 1 : 31;
        { // d=1: MFMA T1(buf1); T2 = 2t*T1 - 1 -> tB -> A-buf0
            SBUF; stageB(3, ic, sbuf);
#pragma unroll
            for (int j = 0; j < 8; j++) tB[j] = fmaf(x2[j], tA[j], -1.0f);
            writeA(tB, 0);
            domfma(rbuf, 1);
            STEP_END(2)
        }
        { // d=2: MFMA T2(buf0); T3 -> tA -> buf1; prefetch next x
            SBUF; stageB(4, ic, sbuf);
            loadx(icn);
#pragma unroll
            for (int j = 0; j < 8; j++) tA[j] = fmaf(x2[j], tB[j], -tA[j]);
            writeA(tA, 1);
            domfma(rbuf, 0);
            STEP_END(4)
        }
#define RSTEP(DST, SRC, ABUF, WBUF, SD, SIC, VM)                         \
        {                                                                \
            SBUF; stageB(SD, SIC, sbuf);                                 \
_Pragma("unroll")                                                        \
            for (int j = 0; j < 8; j++)                                  \
                DST[j] = fmaf(x2[j], SRC[j], -DST[j]);                   \
            writeA(DST, WBUF);                                           \
            domfma(rbuf, ABUF);                                          \
            STEP_END(VM)                                                 \
        }
        RSTEP(tB, tA, 1, 0, 5, ic, 4)    // d=3: MFMA T3, make T4
        RSTEP(tA, tB, 0, 1, 6, ic, 2)    // d=4: MFMA T4, make T5
        RSTEP(tB, tA, 1, 0, 7, ic, 2)    // d=5: MFMA T5, make T6
        RSTEP(tA, tB, 0, 1, 8, ic, 2)    // d=6: MFMA T6, make T7
        RSTEP(tB, tA, 1, 0, 1, icn, 2)   // d=7: MFMA T7, make T8; stage next-ic d=1
#undef RSTEP
        { // d=8: MFMA T8(buf0); tanh(next x) -> T1' -> buf1; stage next-ic d=2
            SBUF; stageB(2, icn, sbuf);
            dotanh();
            writeA(tA, 1);
            domfma(rbuf, 0);
            STEP_END(2)
        }
    }
#undef STEP_END
#undef SBUF

    // epilogue: C/D layout col=lane&31, row=(reg&3)+8*(reg>>2)+4*(lane>>5)
#pragma unroll
    for (int m = 0; m < 2; m++) {
        int rbase = m0 + wr * 64 + m * 32 + ((lane >> 5) << 2);
#pragma unroll
        for (int n = 0; n < 2; n++) {
            int colg = n0 + wc * 64 + n * 32 + (lane & 31);
#pragma unroll
            for (int r = 0; r < 16; r++) {
                int rowg = rbase + (r & 3) + 8 * (r >> 2);
                out[(size_t)rowg * 1024 + colg] = acc[m][n][r];
            }
        }
    }
}

extern "C" void kernel_launch(void* const* d_in, const int* in_sizes, int n_in,
                              void* d_out, int out_size, void* d_ws, size_t ws_size,
                              hipStream_t stream) {
    const float* x  = (const float*)d_in[0];
    const float* W  = (const float*)d_in[1];
    const float* sc = (const float*)d_in[2];
    const float* bi = (const float*)d_in[3];
    float* out = (float*)d_out;

    short* Wt = (short*)d_ws;
    float* b0 = (float*)((char*)d_ws + WS_B0_OFFSET);
    float* part = out;   // colsum partials staged in d_out (fully overwritten by gemm)

    hipLaunchKernelGGL(wt_kernel, dim3(9 * 256), dim3(256), 0, stream, W, Wt);
    hipLaunchKernelGGL(colsum1, dim3(128), dim3(256), 0, stream, W, part);
    hipLaunchKernelGGL(colsum2, dim3(4), dim3(256), 0, stream, part, b0);
    hipLaunchKernelGGL(cheby_gemm, dim3(256), dim3(512), 0, stream, x, Wt, b0, sc, bi, out);
}

// Round 4
// 147.661 us; speedup vs baseline: 1.3831x; 1.3831x over previous
//
#include <hip/hip_runtime.h>
#include <hip/hip_bf16.h>

typedef __attribute__((ext_vector_type(8))) short short8;
typedef __attribute__((ext_vector_type(4))) float f32x4;
typedef __attribute__((ext_vector_type(16))) float f32x16;

#define WS_B0_OFFSET  18874368u   // b0 after Wt2 (9*1024*1024 bf16)

// -------- Phase 0a: W[d][i][o] fp32 -> Wt2[(d*128+q)][o][j] bf16 (i = q*8+j) --------
__global__ void wt2_kernel(const float* __restrict__ W, short* __restrict__ Wt2) {
    int bid = blockIdx.x;            // 0..1151
    int d = bid >> 7, q = bid & 127;
    int t = threadIdx.x;             // 256
    const float* src = W + (size_t)d * 1048576 + (size_t)q * 8 * 1024;
    short* dst = Wt2 + ((size_t)(d * 128 + q) << 13);   // *1024*8
#pragma unroll
    for (int u = 0; u < 4; u++) {
        int o = u * 256 + t;
        short8 v;
#pragma unroll
        for (int j = 0; j < 8; j++)
            v[j] = (short)__bfloat16_as_ushort(__float2bfloat16(src[(size_t)j * 1024 + o]));
        *(short8*)(dst + (size_t)o * 8) = v;
    }
}

// -------- Phase 0b: b0[o] = sum_i W[0][i][o], two-stage --------
__global__ void colsum1(const float* __restrict__ W, float* __restrict__ part) {
    int s = blockIdx.x >> 2;
    int o = (blockIdx.x & 3) * 256 + threadIdx.x;
    const float* p = W + (size_t)s * 32 * 1024 + o;
    float acc = 0.f;
#pragma unroll
    for (int i = 0; i < 32; i++) acc += p[(size_t)i * 1024];
    part[s * 1024 + o] = acc;
}
__global__ void colsum2(const float* __restrict__ part, float* __restrict__ b0) {
    int o = blockIdx.x * 256 + threadIdx.x;
    float acc = 0.f;
#pragma unroll
    for (int s = 0; s < 32; s++) acc += part[s * 1024 + o];
    b0[o] = acc;
}

__device__ __forceinline__ float fast_tanh(float t) {
    float e = __expf(t + t);
    return 1.0f - 2.0f * __builtin_amdgcn_rcpf(e + 1.0f);
}

// -------- Phase 1: fused tanh + Chebyshev + GEMM --------
// 512 thr = 8 waves: wc = wid&3 (64-col slice), kh = wid>>2 (K-half split).
// Tile 128x256; wave computes 128x64 on its k-half (8 x mfma_32x32x16 per step).
// A (bf16 T_d, 128x32) double-buffered in LDS; B direct global->reg (L2-resident),
// ping-pong prefetch one degree ahead. K-split accs merged via LDS at the end.
extern "C" __global__ void __launch_bounds__(512, 2)
cheby_gemm(const float* __restrict__ x, const short* __restrict__ Wt2,
           const float* __restrict__ b0v, const float* __restrict__ scp,
           const float* __restrict__ bip, float* __restrict__ out) {
    __shared__ __align__(16) char lds[49152];   // A: 2x8192 @0; merge: 32KB @16384

    const int tid = threadIdx.x, lane = tid & 63, wid = tid >> 6;
    const int wc = wid & 3, kh = wid >> 2;
    const int tn = blockIdx.x & 3, tm = blockIdx.x >> 2;   // bid%8 -> fixed tn per XCD
    const int m0 = tm << 7, n0 = tn << 8;
    const float sc = scp[0], bi = bip[0];

    // A ownership: row = tid>>2, chunk ac = tid&3 (8 k-elems)
    const int arow = tid >> 2, ac = tid & 3;
    const int wbyte0 = ac * 2048 + ((arow ^ (ac << 1)) << 4);
    const float* xptr = x + (size_t)(m0 + arow) * 1024 + ac * 8;

    // A-frag read base: chunk c = kh*2 + (lane>>5), row rr = lane&31 (+m*32)
    const int cfr = kh * 2 + (lane >> 5);
    const int abase = cfr * 2048 + (((lane & 31) ^ (cfr << 1)) << 4);

    // B byte offsets: Wt2 byte addr = (d*128 + ic*4)*16384 + cfr*16384 + o*16
    const char* wtb = (const char*)Wt2;
    int bofs[2];
#pragma unroll
    for (int n = 0; n < 2; n++)
        bofs[n] = cfr * 16384 + (n0 + wc * 64 + n * 32 + (lane & 31)) * 16;

    auto bld = [&](int dd, int icc, int n) -> short8 {
        return *(const short8*)(wtb + (size_t)(dd * 128 + icc * 4) * 16384 + bofs[n]);
    };

    f32x4 xv0, xv1;
    auto loadx = [&](int icc) {
        const float* p = xptr + (icc << 5);
        xv0 = *(const f32x4*)p;
        xv1 = *(const f32x4*)(p + 4);
    };

    float x2[8], tA[8], tB[8];
    auto dotanh = [&]() {
#pragma unroll
        for (int j = 0; j < 4; j++) {
            tA[j]     = fast_tanh(fmaf(xv0[j], sc, bi));
            tA[j + 4] = fast_tanh(fmaf(xv1[j], sc, bi));
        }
#pragma unroll
        for (int j = 0; j < 8; j++) x2[j] = tA[j] + tA[j];
    };
    auto writeA = [&](const float* t, int wbuf) {
        short8 v;
#pragma unroll
        for (int j = 0; j < 8; j++)
            v[j] = (short)__bfloat16_as_ushort(__float2bfloat16(t[j]));
        *(short8*)(lds + wbuf * 8192 + wbyte0) = v;
    };

    f32x16 acc[4][2];
#pragma unroll
    for (int n = 0; n < 2; n++) {
        float v = (kh == 0) ? b0v[n0 + wc * 64 + n * 32 + (lane & 31)] : 0.0f;
        f32x16 a;
#pragma unroll
        for (int r = 0; r < 16; r++) a[r] = v;
#pragma unroll
        for (int m = 0; m < 4; m++) acc[m][n] = a;
    }

    auto domfma = [&](int rbuf, const short8* bf) {
        short8 af[4];
#pragma unroll
        for (int m = 0; m < 4; m++)
            af[m] = *(const short8*)(lds + rbuf * 8192 + abase + m * 512);
        __builtin_amdgcn_s_setprio(1);
#pragma unroll
        for (int m = 0; m < 4; m++)
#pragma unroll
            for (int n = 0; n < 2; n++)
                acc[m][n] = __builtin_amdgcn_mfma_f32_32x32x16_bf16(af[m], bf[n], acc[m][n], 0, 0, 0);
        __builtin_amdgcn_s_setprio(0);
    };

#define STEP_END                                                  \
    __builtin_amdgcn_sched_barrier(0);                            \
    asm volatile("s_waitcnt lgkmcnt(0)" ::: "memory");            \
    __builtin_amdgcn_s_barrier();                                 \
    __builtin_amdgcn_sched_barrier(0);

    short8 bfA[2], bfB[2];

    // prologue: x(0), B(1) -> bfA, tanh -> T1 -> A-buf0
    loadx(0);
    bfA[0] = bld(1, 0, 0); bfA[1] = bld(1, 0, 1);
    dotanh();
    writeA(tA, 0);
    STEP_END

    for (int ic = 0; ic < 32; ++ic) {
        const int icn = ic < 31 ? ic + 1 : 31;
        { // s=0: use B1/buf0; load B2->bfB; T2 = 2t*T1 - 1 -> buf1
            bfB[0] = bld(2, ic, 0); bfB[1] = bld(2, ic, 1);
#pragma unroll
            for (int j = 0; j < 8; j++) tB[j] = fmaf(x2[j], tA[j], -1.0f);
            writeA(tB, 1);
            domfma(0, bfA);
            STEP_END
        }
        { // s=1: use B2/buf1; load B3->bfA; T3 -> buf0
            bfA[0] = bld(3, ic, 0); bfA[1] = bld(3, ic, 1);
#pragma unroll
            for (int j = 0; j < 8; j++) tA[j] = fmaf(x2[j], tB[j], -tA[j]);
            writeA(tA, 0);
            domfma(1, bfB);
            STEP_END
        }
#define RSTEP(LD, DST, SRC, LBUF, UBUF, RB, WB, XPRE, LIC)        \
        {                                                         \
            LBUF[0] = bld(LD, LIC, 0); LBUF[1] = bld(LD, LIC, 1); \
            if (XPRE) loadx(icn);                                 \
_Pragma("unroll")                                                 \
            for (int j = 0; j < 8; j++)                           \
                DST[j] = fmaf(x2[j], SRC[j], -DST[j]);            \
            writeA(DST, WB);                                      \
            domfma(RB, UBUF);                                     \
            STEP_END                                              \
        }
        RSTEP(4, tB, tA, bfB, bfA, 0, 1, 0, ic)   // s=2: d3, T4
        RSTEP(5, tA, tB, bfA, bfB, 1, 0, 0, ic)   // s=3: d4, T5
        RSTEP(6, tB, tA, bfB, bfA, 0, 1, 0, ic)   // s=4: d5, T6
        RSTEP(7, tA, tB, bfA, bfB, 1, 0, 1, ic)   // s=5: d6, T7; prefetch x(ic+1)
        RSTEP(8, tB, tA, bfB, bfA, 0, 1, 0, ic)   // s=6: d7, T8
#undef RSTEP
        { // s=7: use B8/buf1; load B1(ic+1)->bfB... wait parity: s=7 loads bfA
            // s odd -> load bfA, use bfB
            bfA[0] = bld(1, icn, 0); bfA[1] = bld(1, icn, 1);
            dotanh();                 // T1' from x(ic+1)
            writeA(tA, 0);
            domfma(1, bfB);
            STEP_END
        }
    }
#undef STEP_END

    // -------- K-split merge (kh=1 accs added into kh=0 accs), chunked by m --------
#pragma unroll
    for (int m = 0; m < 4; m++) {
        if (kh == 1) {
#pragma unroll
            for (int n = 0; n < 2; n++) {
                char* base = lds + 16384 + (wc * 2 + n) * 4096 + lane * 64;
#pragma unroll
                for (int q = 0; q < 4; q++) {
                    f32x4 v = {acc[m][n][q * 4 + 0], acc[m][n][q * 4 + 1],
                               acc[m][n][q * 4 + 2], acc[m][n][q * 4 + 3]};
                    *(f32x4*)(base + ((q ^ (lane & 3)) << 4)) = v;
                }
            }
        }
        __syncthreads();
        if (kh == 0) {
#pragma unroll
            for (int n = 0; n < 2; n++) {
                const char* base = lds + 16384 + (wc * 2 + n) * 4096 + lane * 64;
#pragma unroll
                for (int q = 0; q < 4; q++) {
                    f32x4 v = *(const f32x4*)(base + ((q ^ (lane & 3)) << 4));
#pragma unroll
                    for (int e = 0; e < 4; e++) acc[m][n][q * 4 + e] += v[e];
                }
            }
        }
        __syncthreads();
    }

    // -------- store (kh=0 waves) : C/D col=lane&31, row=(r&3)+8*(r>>2)+4*(lane>>5) --------
    if (kh == 0) {
#pragma unroll
        for (int m = 0; m < 4; m++) {
            int rbase = m0 + m * 32 + ((lane >> 5) << 2);
#pragma unroll
            for (int n = 0; n < 2; n++) {
                int colg = n0 + wc * 64 + n * 32 + (lane & 31);
#pragma unroll
                for (int r = 0; r < 16; r++) {
                    int rowg = rbase + (r & 3) + 8 * (r >> 2);
                    out[(size_t)rowg * 1024 + colg] = acc[m][n][r];
                }
            }
        }
    }
}

extern "C" void kernel_launch(void* const* d_in, const int* in_sizes, int n_in,
                              void* d_out, int out_size, void* d_ws, size_t ws_size,
                              hipStream_t stream) {
    const float* x  = (const float*)d_in[0];
    const float* W  = (const float*)d_in[1];
    const float* sc = (const float*)d_in[2];
    const float* bi = (const float*)d_in[3];
    float* out = (float*)d_out;

    short* Wt2 = (short*)d_ws;
    float* b0  = (float*)((char*)d_ws + WS_B0_OFFSET);
    float* part = out;   // colsum partials staged in d_out (fully overwritten by gemm)

    hipLaunchKernelGGL(wt2_kernel, dim3(9 * 128), dim3(256), 0, stream, W, Wt2);
    hipLaunchKernelGGL(colsum1, dim3(128), dim3(256), 0, stream, W, part);
    hipLaunchKernelGGL(colsum2, dim3(4), dim3(256), 0, stream, part, b0);
    hipLaunchKernelGGL(cheby_gemm, dim3(256), dim3(512), 0, stream, x, Wt2, b0, sc, bi, out);
}